// Round 1
// baseline (763.402 us; speedup 1.0000x reference)
//
#include <hip/hip_runtime.h>
#include <math.h>

// AttentionAggregator2 fused kernel for MI355X (gfx950).
// Strategy: memory-bound problem (~695 MB traffic, 16.4 GF). All GEMM-shaped
// compute in f16 MFMA (fp32 accum) so the kernel rides the HBM roofline.
// Key algebra: ws[n,k] = tanh(ne@W2a) . u[n], u[n] = M^T tanh(x@W1a),
// M = W1b @ W2b^T  (removes the [N*K,32]x[32,32] GEMM entirely).

typedef _Float16 half_t;
typedef __attribute__((ext_vector_type(4))) _Float16 half4_t;
typedef __attribute__((ext_vector_type(8))) _Float16 half8_t;
typedef __attribute__((ext_vector_type(4))) float f32x4;

#define NN   50000
#define GK   16     // neighbors per node
#define DIN  128
#define DED  64
#define DNE  192    // DIN + DED
#define G    8      // nodes per block
#define NEP  200    // padded LDS row length in halfs (400 B = 25*16B, b128-aligned)

// workspace byte offsets (written fresh by setup_kernel every launch)
#define WS_M    0        // 32x32 f32: M = W1b @ W2b^T
#define WS_W1A  4096     // 2 tiles * 4 ksteps * 64 lanes * 8 halfs
#define WS_W2A  12288    // 2 * 6 * 512
#define WS_WFX  24576    // 8 * 4 * 512
#define WS_WFN  57344    // 8 * 6 * 512   (total 106496 B of d_ws used)

// Pre-swizzle weight matrix W[K x ncol] into MFMA B-fragment order:
// frag element ((t*S+s)*64 + lane)*8 + j  <=  W[32s + (lane>>4)*8 + j][16t + (lane&15)]
__device__ __forceinline__ void swz(const float* __restrict__ W, int ncol, int S,
                                    half_t* __restrict__ dst, int tid, int nth) {
  int T = ncol >> 4;
  int total = T * S * 512;
  for (int i = tid; i < total; i += nth) {
    int j = i & 7;
    int l = (i >> 3) & 63;
    int rest = i >> 9;
    int s = rest % S;
    int t = rest / S;
    int k = 32 * s + (l >> 4) * 8 + j;
    int n = 16 * t + (l & 15);
    dst[i] = (half_t)W[k * ncol + n];
  }
}

__global__ void setup_kernel(const float* __restrict__ W1a, const float* __restrict__ W1b,
                             const float* __restrict__ W2a, const float* __restrict__ W2b,
                             const float* __restrict__ Wfx, const float* __restrict__ Wfn,
                             unsigned char* __restrict__ ws) {
  int tid = blockIdx.x * blockDim.x + threadIdx.x;
  int nth = gridDim.x * blockDim.x;
  float* Mm = (float*)(ws + WS_M);
  for (int i = tid; i < 1024; i += nth) {        // M[a][h] = sum_h2 W1b[a][h2]*W2b[h][h2]
    int a = i >> 5, h = i & 31;
    float acc = 0.f;
    for (int h2 = 0; h2 < 32; ++h2)
      acc = fmaf(W1b[a * 32 + h2], W2b[h * 32 + h2], acc);
    Mm[i] = acc;
  }
  swz(W1a, 32, 4, (half_t*)(ws + WS_W1A), tid, nth);
  swz(W2a, 32, 6, (half_t*)(ws + WS_W2A), tid, nth);
  swz(Wfx, 128, 4, (half_t*)(ws + WS_WFX), tid, nth);
  swz(Wfn, 128, 6, (half_t*)(ws + WS_WFN), tid, nth);
}

__device__ __forceinline__ half8_t cvt8(float4 a, float4 b) {
  half8_t r;
  r[0] = (half_t)a.x; r[1] = (half_t)a.y; r[2] = (half_t)a.z; r[3] = (half_t)a.w;
  r[4] = (half_t)b.x; r[5] = (half_t)b.y; r[6] = (half_t)b.z; r[7] = (half_t)b.w;
  return r;
}

__device__ __forceinline__ float elu(float v) { return v > 0.f ? v : expm1f(v); }

__global__ __launch_bounds__(512, 4)
void attn_kernel(const float* __restrict__ x, const float* __restrict__ neibs,
                 const float* __restrict__ edge, const float* __restrict__ mask,
                 const unsigned char* __restrict__ ws, float* __restrict__ out) {
  __shared__ half_t neL[G * GK * NEP];   // 51200 B: ne (f16) per node, row-padded
  __shared__ half_t aggL[16 * NEP];      // 6400 B: agg rows (16 for full M=16 A-frags)
  __shared__ float t1L[G][33];
  __shared__ float uL[G][33];
  __shared__ float scL[G][16];
  __shared__ float wsmL[G][16];

  const int tid = threadIdx.x;
  const int wave = tid >> 6;
  const int lane = tid & 63;
  const int l15 = lane & 15;
  const int q = lane >> 4;
  const int n0 = blockIdx.x * G;

  const float* Mm = (const float*)(ws + WS_M);
  const half_t* w1a = (const half_t*)(ws + WS_W1A);
  const half_t* w2a = (const half_t*)(ws + WS_W2A);
  const half_t* wfx = (const half_t*)(ws + WS_WFX);
  const half_t* wfn = (const half_t*)(ws + WS_WFN);

  // ---- stage ne = [neibs | edge] -> LDS f16 (single HBM read of ne) ----
  {
    const float4* gn = (const float4*)(neibs + (size_t)n0 * (GK * DIN));
#pragma unroll
    for (int c = 0; c < 8; ++c) {
      int v = c * 512 + tid;               // 4096 float4 per block, fully coalesced
      float4 f = gn[v];
      int g = v >> 9, rem = v & 511, k = rem >> 5, d4 = rem & 31;
      half4_t h = { (half_t)f.x, (half_t)f.y, (half_t)f.z, (half_t)f.w };
      *(half4_t*)&neL[(g * GK + k) * NEP + d4 * 4] = h;
    }
    const float4* ge = (const float4*)(edge + (size_t)n0 * (GK * DED));
#pragma unroll
    for (int c = 0; c < 4; ++c) {
      int v = c * 512 + tid;               // 2048 float4 per block
      float4 f = ge[v];
      int g = v >> 8, rem = v & 255, k = rem >> 4, d4 = rem & 15;
      half4_t h = { (half_t)f.x, (half_t)f.y, (half_t)f.z, (half_t)f.w };
      *(half4_t*)&neL[(g * GK + k) * NEP + DIN + d4 * 4] = h;
    }
    for (int i = tid; i < 16 * NEP / 2; i += 512)   // zero agg (rows 8..15 stay 0)
      ((unsigned int*)aggL)[i] = 0u;
  }

  // ---- phase 0 (waves 0,1): t1 = tanh(x @ W1a), tile = wave ----
  if (wave < 2) {
    f32x4 acc = {0.f, 0.f, 0.f, 0.f};
    int row = n0 + l15; if (row >= NN) row = NN - 1;   // clamped; rows>=G discarded
    const float* xrow = x + (size_t)row * DIN;
#pragma unroll
    for (int s = 0; s < 4; ++s) {
      float4 a0 = *(const float4*)(xrow + 32 * s + 8 * q);
      float4 a1 = *(const float4*)(xrow + 32 * s + 8 * q + 4);
      half8_t A = cvt8(a0, a1);
      half8_t B = *(const half8_t*)(w1a + ((size_t)(wave * 4 + s) * 64 + lane) * 8);
      acc = __builtin_amdgcn_mfma_f32_16x16x32_f16(A, B, acc, 0, 0, 0);
    }
#pragma unroll
    for (int r = 0; r < 4; ++r) {
      int g = 4 * q + r;                   // C row = node
      if (g < G) t1L[g][wave * 16 + l15] = tanhf(acc[r]);
    }
  }
  __syncthreads();

  // ---- u[g][h] = sum_a t1[g][a] * M[a][h] ----
  if (tid < G * 32) {
    int g = tid >> 5, h = tid & 31;
    float acc = 0.f;
#pragma unroll
    for (int a = 0; a < 32; ++a)
      acc = fmaf(t1L[g][a], Mm[a * 32 + h], acc);   // t1 broadcast, M coalesced
    uL[g][h] = acc;
  }
  __syncthreads();

  // ---- phase 1+2: wave w owns node w. scores + softmax + aggregation ----
  {
    const int g = wave;
    f32x4 acc0 = {0.f, 0.f, 0.f, 0.f}, acc1 = {0.f, 0.f, 0.f, 0.f};
    const half_t* nerow = &neL[(g * GK + l15) * NEP];   // A row = neighbor k = l15
#pragma unroll
    for (int s = 0; s < 6; ++s) {
      half8_t A  = *(const half8_t*)(nerow + 32 * s + 8 * q);
      half8_t B0 = *(const half8_t*)(w2a + ((size_t)(0 * 6 + s) * 64 + lane) * 8);
      half8_t B1 = *(const half8_t*)(w2a + ((size_t)(1 * 6 + s) * 64 + lane) * 8);
      acc0 = __builtin_amdgcn_mfma_f32_16x16x32_f16(A, B0, acc0, 0, 0, 0);
      acc1 = __builtin_amdgcn_mfma_f32_16x16x32_f16(A, B1, acc1, 0, 0, 0);
    }
    // s[k] = sum_h tanh(P[k][h]) * u[h];  lane holds col h=l15(+16), rows k=4q+r
    float u0 = uL[g][l15], u1 = uL[g][16 + l15];
    float sv[4];
#pragma unroll
    for (int r = 0; r < 4; ++r)
      sv[r] = tanhf(acc0[r]) * u0 + tanhf(acc1[r]) * u1;
#pragma unroll
    for (int off = 1; off <= 8; off <<= 1)
#pragma unroll
      for (int r = 0; r < 4; ++r)
        sv[r] += __shfl_xor(sv[r], off);   // reduce over 16 cols (h)
    if (l15 == 0)
#pragma unroll
      for (int r = 0; r < 4; ++r)
        scL[g][4 * q + r] = sv[r];
  }
  __syncthreads();

  {
    const int g = wave;
    // masked softmax over the node's 16 scores (lanes 0..15)
    float sc = -3.4e38f;
    if (lane < 16)
      sc = scL[g][lane] - 9999999.0f * mask[(size_t)(n0 + g) * GK + lane];
    float mx = sc;
#pragma unroll
    for (int off = 1; off <= 8; off <<= 1) mx = fmaxf(mx, __shfl_xor(mx, off));
    float e = (lane < 16) ? expf(sc - mx) : 0.f;
    float sm = e;
#pragma unroll
    for (int off = 1; off <= 8; off <<= 1) sm += __shfl_xor(sm, off);
    if (lane < 16) wsmL[g][lane] = e / sm;

    // agg[d] = sum_k ws[k] * ne[k][d];  lane owns d = lane, lane+64, lane+128
    float a0 = 0.f, a1 = 0.f, a2 = 0.f;
    for (int k = 0; k < GK; ++k) {
      float wv = wsmL[g][k];                        // same-wave RAW; LDS broadcast
      const half_t* r_ = &neL[(g * GK + k) * NEP];
      a0 = fmaf(wv, (float)r_[lane], a0);
      a1 = fmaf(wv, (float)r_[64 + lane], a1);
      a2 = fmaf(wv, (float)r_[128 + lane], a2);
    }
    aggL[g * NEP + lane] = (half_t)a0;
    aggL[g * NEP + 64 + lane] = (half_t)a1;
    aggL[g * NEP + 128 + lane] = (half_t)a2;
  }
  __syncthreads();

  // ---- phase 4: out = elu([x @ Wfx, agg @ Wfn]); wave w = col-tile w ----
  {
    f32x4 accx = {0.f, 0.f, 0.f, 0.f}, accn = {0.f, 0.f, 0.f, 0.f};
    int row = n0 + l15; if (row >= NN) row = NN - 1;
    const float* xrow = x + (size_t)row * DIN;
#pragma unroll
    for (int s = 0; s < 4; ++s) {
      float4 a0 = *(const float4*)(xrow + 32 * s + 8 * q);
      float4 a1 = *(const float4*)(xrow + 32 * s + 8 * q + 4);
      half8_t A = cvt8(a0, a1);                     // L1-hot reload of x
      half8_t B = *(const half8_t*)(wfx + ((size_t)(wave * 4 + s) * 64 + lane) * 8);
      accx = __builtin_amdgcn_mfma_f32_16x16x32_f16(A, B, accx, 0, 0, 0);
    }
#pragma unroll
    for (int s = 0; s < 6; ++s) {
      half8_t A = *(const half8_t*)(&aggL[l15 * NEP + 32 * s + 8 * q]);
      half8_t B = *(const half8_t*)(wfn + ((size_t)(wave * 6 + s) * 64 + lane) * 8);
      accn = __builtin_amdgcn_mfma_f32_16x16x32_f16(A, B, accn, 0, 0, 0);
    }
#pragma unroll
    for (int r = 0; r < 4; ++r) {
      int m = 4 * q + r;                   // C row = node
      if (m < G) {
        size_t base = (size_t)(n0 + m) * 256;
        out[base + wave * 16 + l15] = elu(accx[r]);
        out[base + 128 + wave * 16 + l15] = elu(accn[r]);
      }
    }
  }
}

extern "C" void kernel_launch(void* const* d_in, const int* in_sizes, int n_in,
                              void* d_out, int out_size, void* d_ws, size_t ws_size,
                              hipStream_t stream) {
  const float* x     = (const float*)d_in[0];
  const float* neibs = (const float*)d_in[1];
  const float* edge  = (const float*)d_in[2];
  const float* mask  = (const float*)d_in[3];
  const float* W1a   = (const float*)d_in[4];
  const float* W1b   = (const float*)d_in[5];
  const float* W2a   = (const float*)d_in[6];
  const float* W2b   = (const float*)d_in[7];
  const float* Wfx   = (const float*)d_in[8];
  const float* Wfn   = (const float*)d_in[9];
  float* out = (float*)d_out;
  unsigned char* ws = (unsigned char*)d_ws;

  hipLaunchKernelGGL(setup_kernel, dim3(64), dim3(256), 0, stream,
                     W1a, W1b, W2a, W2b, Wfx, Wfn, ws);
  hipLaunchKernelGGL(attn_kernel, dim3(NN / G), dim3(512), 0, stream,
                     x, neibs, edge, mask, ws, out);
}